// Round 2
// baseline (51435.864 us; speedup 1.0000x reference)
//
#include <hip/hip_runtime.h>
#include <cstdint>
#include <cstddef>

#define T_STEPS 512
#define BATCH   64
#define HD      1024          // IN_DIM == H_DIM == 1024
#define BH      (BATCH * HD)  // 65536

using half8   = __attribute__((ext_vector_type(8))) _Float16;  // MFMA f16 A/B frag
using floatx4 = __attribute__((ext_vector_type(4))) float;     // MFMA C/D frag
using float4v = __attribute__((ext_vector_type(4))) float;

__device__ __forceinline__ float sigmoidf_(float x) {
    return 1.0f / (1.0f + __expf(-x));
}

// c0 (fp32) -> fp32 state buffer 0 + f16 hi/lo split copies
__global__ void init_c(const float* __restrict__ c0,
                       float* __restrict__ cf,
                       _Float16* __restrict__ ch,
                       _Float16* __restrict__ cl) {
    int i = blockIdx.x * 256 + threadIdx.x;
    if (i < BH) {
        float v = c0[i];
        cf[i] = v;
        _Float16 h = (_Float16)v;
        ch[i] = h;
        cl[i] = (_Float16)(v - (float)h);
    }
}

// Pre-split weights (tier-1 only): Wx -> f16, Wh -> f16 hi + lo
__global__ void prep_w(const float* __restrict__ Wx, const float* __restrict__ Wh,
                       _Float16* __restrict__ wx16,
                       _Float16* __restrict__ whh, _Float16* __restrict__ whl) {
    int i = blockIdx.x * 256 + threadIdx.x;
    if (i < 4 * HD * HD) {
        wx16[i] = (_Float16)Wx[i];
        float w = Wh[i];
        _Float16 h = (_Float16)w;
        whh[i] = h;
        whl[i] = (_Float16)(w - (float)h);
    }
}

__device__ __forceinline__ half8 cvt_h8(float4v a, float4v b) {
    half8 r;
    r[0] = (_Float16)a[0]; r[1] = (_Float16)a[1];
    r[2] = (_Float16)a[2]; r[3] = (_Float16)a[3];
    r[4] = (_Float16)b[0]; r[5] = (_Float16)b[1];
    r[6] = (_Float16)b[2]; r[7] = (_Float16)b[3];
    return r;
}

// One time step. grid = 64 blocks (16 output cols each, all 4 gates, all 64 batch).
// block = 1024 threads = 16 waves; wave w: gate g = w&3, batch-tile mt = w>>2.
// Each wave: one 16x16 MFMA tile. X-part: single f16 product (err ~7e-4).
// c-part: 3-product f16 split (fp32-exact to ~2^-22).
template<bool PRE>
__global__ __launch_bounds__(1024) void lstm_step(
    const float* __restrict__ X,      // [T,B,IN] fp32
    const float* __restrict__ h0,     // [B,H]
    const float* __restrict__ Wx,     // [4H,IN] fp32
    const float* __restrict__ Wh,     // [4H,H]
    const float* __restrict__ bias,   // [4H]
    const int*  __restrict__ mask,    // [T,B]
    const _Float16* __restrict__ wx16,  // [4H,IN] (PRE)
    const _Float16* __restrict__ whh,   // [4H,H]  (PRE)
    const _Float16* __restrict__ whl,   // [4H,H]  (PRE)
    float* __restrict__ cf,           // [2][BH] fp32 cell ping-pong
    _Float16* __restrict__ chbuf,     // [2][BH] f16 hi
    _Float16* __restrict__ clbuf,     // [2][BH] f16 lo
    float* __restrict__ out,          // [T*BH] hiddens ++ [BH] h_last ++ [BH] c_last
    int t)
{
    __shared__ float lds_pre[4][64][16];   // [gate][batch][col] 16 KB

    const int tid  = threadIdx.x;
    const int wave = tid >> 6;
    const int lane = tid & 63;
    const int g    = wave & 3;
    const int mt   = wave >> 2;
    const int j0   = blockIdx.x * 16;

    const int cur = t & 1;
    const float*    cf_prev = cf    + (size_t)cur * BH;
    const _Float16* ch_prev = chbuf + (size_t)cur * BH;
    const _Float16* cl_prev = clbuf + (size_t)cur * BH;
    float*    cf_next = cf    + (size_t)(cur ^ 1) * BH;
    _Float16* ch_next = chbuf + (size_t)(cur ^ 1) * BH;
    _Float16* cl_next = clbuf + (size_t)(cur ^ 1) * BH;

    // gfx950 16x16x32 fragment layouts (verified m89/m120):
    //   A: lane holds A[m=lane&15][k=(lane>>4)*8 + j], j=0..7
    //   B: lane holds W-row n=lane&15 (B^T row), same k mapping
    //   C/D: col=lane&15, row=(lane>>4)*4 + reg
    const int arow = mt * 16 + (lane & 15);          // batch row
    const int brow = g * HD + j0 + (lane & 15);      // W row (output col)
    const int koff = (lane >> 4) * 8;

    floatx4 acc = {0.f, 0.f, 0.f, 0.f};

    // ---- X part: pre += X[t] @ Wx^T (single-product f16) ----
    {
        const float* xp = X + (size_t)t * BH + (size_t)arow * HD + koff;
        if (PRE) {
            const _Float16* wp = wx16 + (size_t)brow * HD + koff;
            #pragma unroll 4
            for (int k = 0; k < HD; k += 32) {
                float4v x0 = *(const float4v*)(xp + k);
                float4v x1 = *(const float4v*)(xp + k + 4);
                half8 a = cvt_h8(x0, x1);
                half8 b = *(const half8*)(wp + k);
                acc = __builtin_amdgcn_mfma_f32_16x16x32_f16(a, b, acc, 0, 0, 0);
            }
        } else {
            const float* wp = Wx + (size_t)brow * HD + koff;
            #pragma unroll 4
            for (int k = 0; k < HD; k += 32) {
                float4v x0 = *(const float4v*)(xp + k);
                float4v x1 = *(const float4v*)(xp + k + 4);
                float4v w0 = *(const float4v*)(wp + k);
                float4v w1 = *(const float4v*)(wp + k + 4);
                half8 a = cvt_h8(x0, x1);
                half8 b = cvt_h8(w0, w1);
                acc = __builtin_amdgcn_mfma_f32_16x16x32_f16(a, b, acc, 0, 0, 0);
            }
        }
    }

    // ---- c part: pre += c_prev @ Wh^T (3-product f16 split, ~fp32 exact) ----
    {
        const _Float16* chp = ch_prev + (size_t)arow * HD + koff;
        const _Float16* clp = cl_prev + (size_t)arow * HD + koff;
        if (PRE) {
            const _Float16* whp = whh + (size_t)brow * HD + koff;
            const _Float16* wlp = whl + (size_t)brow * HD + koff;
            #pragma unroll 4
            for (int k = 0; k < HD; k += 32) {
                half8 ah = *(const half8*)(chp + k);
                half8 al = *(const half8*)(clp + k);
                half8 bh = *(const half8*)(whp + k);
                half8 bl = *(const half8*)(wlp + k);
                acc = __builtin_amdgcn_mfma_f32_16x16x32_f16(ah, bh, acc, 0, 0, 0);
                acc = __builtin_amdgcn_mfma_f32_16x16x32_f16(al, bh, acc, 0, 0, 0);
                acc = __builtin_amdgcn_mfma_f32_16x16x32_f16(ah, bl, acc, 0, 0, 0);
            }
        } else {
            const float* whp = Wh + (size_t)brow * HD + koff;
            #pragma unroll 4
            for (int k = 0; k < HD; k += 32) {
                half8 ah = *(const half8*)(chp + k);
                half8 al = *(const half8*)(clp + k);
                float4v w0 = *(const float4v*)(whp + k);
                float4v w1 = *(const float4v*)(whp + k + 4);
                half8 bh = cvt_h8(w0, w1);
                float4v r0, r1;
                r0[0] = w0[0] - (float)bh[0]; r0[1] = w0[1] - (float)bh[1];
                r0[2] = w0[2] - (float)bh[2]; r0[3] = w0[3] - (float)bh[3];
                r1[0] = w1[0] - (float)bh[4]; r1[1] = w1[1] - (float)bh[5];
                r1[2] = w1[2] - (float)bh[6]; r1[3] = w1[3] - (float)bh[7];
                half8 bl = cvt_h8(r0, r1);
                acc = __builtin_amdgcn_mfma_f32_16x16x32_f16(ah, bh, acc, 0, 0, 0);
                acc = __builtin_amdgcn_mfma_f32_16x16x32_f16(al, bh, acc, 0, 0, 0);
                acc = __builtin_amdgcn_mfma_f32_16x16x32_f16(ah, bl, acc, 0, 0, 0);
            }
        }
    }

    // scatter pre-activations to LDS
    {
        const int q = lane >> 4, col = lane & 15;
        lds_pre[g][mt * 16 + q * 4 + 0][col] = acc[0];
        lds_pre[g][mt * 16 + q * 4 + 1][col] = acc[1];
        lds_pre[g][mt * 16 + q * 4 + 2][col] = acc[2];
        lds_pre[g][mt * 16 + q * 4 + 3][col] = acc[3];
    }
    __syncthreads();

    // epilogue: one output element per thread (64 batch x 16 cols)
    {
        const int bl = tid >> 4;
        const int n  = tid & 15;
        const int j  = j0 + n;

        float pg[4];
        #pragma unroll
        for (int gg = 0; gg < 4; gg++)
            pg[gg] = lds_pre[gg][bl][n] + bias[gg * HD + j];

        const float c_old = cf_prev[bl * HD + j];
        const float i_g = sigmoidf_(pg[0]);
        const float f_g = sigmoidf_(pg[1]);
        const float o_g = sigmoidf_(pg[2]);
        const float g_g = tanhf(pg[3]);

        const float c_new = f_g * c_old + i_g * g_g;
        const float h_new = o_g * tanhf(c_new);

        const int mv = mask[t * BATCH + bl];
        const float h_prev = (t == 0)
            ? h0[bl * HD + j]
            : out[(size_t)(t - 1) * BH + bl * HD + j];

        const float h_out = mv ? h_new : h_prev;
        const float c_out = mv ? c_new : c_old;

        cf_next[bl * HD + j] = c_out;
        _Float16 hh = (_Float16)c_out;
        ch_next[bl * HD + j] = hh;
        cl_next[bl * HD + j] = (_Float16)(c_out - (float)hh);
        out[(size_t)t * BH + bl * HD + j] = h_out;

        if (t == T_STEPS - 1) {
            const size_t tail = (size_t)T_STEPS * BH;
            out[tail + bl * HD + j]      = h_out;   // h_last
            out[tail + BH + bl * HD + j] = c_out;   // c_last
        }
    }
}

extern "C" void kernel_launch(void* const* d_in, const int* in_sizes, int n_in,
                              void* d_out, int out_size, void* d_ws, size_t ws_size,
                              hipStream_t stream) {
    const float* X    = (const float*)d_in[0];
    const float* h0   = (const float*)d_in[1];
    const float* c0   = (const float*)d_in[2];
    const int*   mask = (const int*)  d_in[3];
    const float* Wx   = (const float*)d_in[4];
    const float* Wh   = (const float*)d_in[5];
    const float* bias = (const float*)d_in[6];
    float* out = (float*)d_out;

    char* ws = (char*)d_ws;
    // state: fp32 ping-pong (512KB) + f16 hi (256KB) + f16 lo (256KB)
    float*    cf = (float*)ws;
    _Float16* ch = (_Float16*)(ws + 524288);
    _Float16* cl = (_Float16*)(ws + 786432);

    // tier-1: pre-split weights in ws (needs 25 MB total)
    const size_t W_ELEMS = (size_t)4 * HD * HD;  // 4 Mi
    const bool pre = ws_size >= (size_t)(1048576 + 3 * W_ELEMS * sizeof(_Float16));
    _Float16* wx16 = (_Float16*)(ws + 1048576);
    _Float16* whh  = wx16 + W_ELEMS;
    _Float16* whl  = whh + W_ELEMS;

    init_c<<<dim3((BH + 255) / 256), dim3(256), 0, stream>>>(c0, cf, ch, cl);
    if (pre) {
        prep_w<<<dim3((int)((W_ELEMS + 255) / 256)), dim3(256), 0, stream>>>(
            Wx, Wh, wx16, whh, whl);
        for (int t = 0; t < T_STEPS; t++)
            lstm_step<true><<<dim3(64), dim3(1024), 0, stream>>>(
                X, h0, Wx, Wh, bias, mask, wx16, whh, whl, cf, ch, cl, out, t);
    } else {
        for (int t = 0; t < T_STEPS; t++)
            lstm_step<false><<<dim3(64), dim3(1024), 0, stream>>>(
                X, h0, Wx, Wh, bias, mask, nullptr, nullptr, nullptr, cf, ch, cl, out, t);
    }
}

// Round 3
// 16148.596 us; speedup vs baseline: 3.1852x; 3.1852x over previous
//
#include <hip/hip_runtime.h>
#include <cstdint>
#include <cstddef>

#define T_STEPS 512
#define BATCH   64
#define HD      1024
#define BH      (BATCH * HD)   // 65536
#define NBLK    256

using half8   = __attribute__((ext_vector_type(8))) _Float16;
using floatx4 = __attribute__((ext_vector_type(4))) float;
using float4v = __attribute__((ext_vector_type(4))) float;

__device__ __forceinline__ float sigmoidf_(float x) { return 1.0f / (1.0f + __expf(-x)); }

__device__ __forceinline__ half8 cvt_h8(float4v a, float4v b) {
    half8 r;
    r[0] = (_Float16)a[0]; r[1] = (_Float16)a[1];
    r[2] = (_Float16)a[2]; r[3] = (_Float16)a[3];
    r[4] = (_Float16)b[0]; r[5] = (_Float16)b[1];
    r[6] = (_Float16)b[2]; r[7] = (_Float16)b[3];
    return r;
}

// ---------------- workspace layout ----------------
// [0, 24KB)      barrier: group counters (slot*8+g) @0, root counters @20KB
// [24KB, ..)     c hi ping-pong  2*BH f16 = 256KB
//                c lo ping-pong  2*BH f16 = 256KB
// [1MB)          wx16  8MB ; whh 8MB ; whl 8MB
// [25MB)         xh (tier A): T*BH f16 = 64MB
static const size_t BAR_GRP_OFF  = 0;
static const size_t BAR_ROOT_OFF = 20480;
static const size_t CH_OFF  = 24576;
static const size_t CL_OFF  = CH_OFF + (size_t)2 * BH * 2;
static const size_t WX_OFF  = 1u << 20;
static const size_t WHH_OFF = WX_OFF  + (size_t)8 * 1024 * 1024;
static const size_t WHL_OFF = WHH_OFF + (size_t)8 * 1024 * 1024;
static const size_t XH_OFF  = WHL_OFF + (size_t)8 * 1024 * 1024;   // 25MB
static const size_t TIER_A_WS = XH_OFF + (size_t)T_STEPS * BH * 2; // 89MB
static const size_t TIER_B_WS = XH_OFF;                            // 25MB

// ---------------- prep kernels ----------------
__global__ void prep_zero(int* bar) {
    int i = blockIdx.x * 256 + threadIdx.x;
    if (i < 6144) bar[i] = 0;   // zero 24KB barrier region
}

__global__ void prep_w(const float* __restrict__ Wx, const float* __restrict__ Wh,
                       _Float16* __restrict__ wx16,
                       _Float16* __restrict__ whh, _Float16* __restrict__ whl) {
    int i = blockIdx.x * 256 + threadIdx.x;
    if (i < 4 * HD * HD) {
        wx16[i] = (_Float16)Wx[i];
        float w = Wh[i];
        _Float16 h = (_Float16)w;
        whh[i] = h;
        whl[i] = (_Float16)(w - (float)h);
    }
}

__global__ void prep_x(const float* __restrict__ X, _Float16* __restrict__ xh) {
    size_t i = (size_t)blockIdx.x * 256 + threadIdx.x;
    if (i < (size_t)T_STEPS * BH) xh[i] = (_Float16)X[i];
}

// ---------------- grid barrier (tree: 8 groups of 32 -> root) ----------------
__device__ __forceinline__ void grid_bar(int* grp, int* root, int slot) {
    __syncthreads();   // all block lanes done with stores (vmcnt drained per-wave)
    if (threadIdx.x == 0) {
        int g = blockIdx.x >> 5;
        int v = __hip_atomic_fetch_add(&grp[slot * 8 + g], 1,
                                       __ATOMIC_ACQ_REL, __HIP_MEMORY_SCOPE_AGENT);
        if (v == 31)
            __hip_atomic_fetch_add(&root[slot], 1,
                                   __ATOMIC_ACQ_REL, __HIP_MEMORY_SCOPE_AGENT);
        while (__hip_atomic_load(&root[slot], __ATOMIC_RELAXED,
                                 __HIP_MEMORY_SCOPE_AGENT) < 8)
            __builtin_amdgcn_s_sleep(2);
        (void)__hip_atomic_load(&root[slot], __ATOMIC_ACQUIRE,
                                __HIP_MEMORY_SCOPE_AGENT);
    }
    __syncthreads();
}

// ---------------- persistent LSTM kernel ----------------
// grid = 256 blocks (1/CU), block = 1024 threads = 16 waves.
// Block owns j0..j0+3 (4 cols x 4 gates = 16 W rows = one MFMA n-tile,
// n = g*4 + jj). Wave w: batch-tile mt=w&3, K-chunk kh=w>>2 (256 wide).
// whh in LDS; wx16/whl streamed from L2; c hi/lo ping-pong in ws.
template<bool XF16>
__global__ __launch_bounds__(1024, 4) void lstm_persist(
    const float* __restrict__ X, const _Float16* __restrict__ xh,
    const float* __restrict__ h0, const float* __restrict__ c0,
    const float* __restrict__ bias, const int* __restrict__ mask,
    const _Float16* __restrict__ wx16, const _Float16* __restrict__ whh,
    const _Float16* __restrict__ whl,
    _Float16* __restrict__ chg, _Float16* __restrict__ clg,
    int* __restrict__ barg, int* __restrict__ barr,
    float* __restrict__ out)
{
    __shared__ _Float16 s_wh[16 * 1032];        // whh rows, pad 8 f16 (33KB)
    __shared__ float    s_pre[16][16][17];      // [wave][m][n] partials (17.4KB)
    __shared__ float    s_h[256], s_c[256];     // owned h/c fp32 state

    const int tid  = threadIdx.x;
    const int wave = tid >> 6;
    const int lane = tid & 63;
    const int j0   = blockIdx.x * 4;

    // --- stage whh rows into LDS ---
    for (int idx = tid; idx < 2048; idx += 1024) {
        int n  = idx >> 7;
        int kk = (idx & 127) << 3;
        int r  = (n >> 2) * HD + j0 + (n & 3);
        *(half8*)&s_wh[n * 1032 + kk] = *(const half8*)(whh + (size_t)r * HD + kk);
    }

    // --- init owned h/c state, publish initial c hi/lo, preload bias ---
    float biasr[4] = {0.f, 0.f, 0.f, 0.f};
    if (tid < 256) {
        int b = tid >> 2, jj = tid & 3, j = j0 + jj;
        float cv = c0[b * HD + j];
        s_c[tid] = cv;
        s_h[tid] = h0[b * HD + j];
        _Float16 hi = (_Float16)cv;
        chg[b * HD + j] = hi;
        clg[b * HD + j] = (_Float16)(cv - (float)hi);
        #pragma unroll
        for (int g = 0; g < 4; g++) biasr[g] = bias[g * HD + j];
    }
    grid_bar(barg, barr, 0);

    const int mt    = wave & 3;
    const int kh    = wave >> 2;
    const int arow  = mt * 16 + (lane & 15);
    const int nn    = lane & 15;
    const int q     = lane >> 4;
    const int kbase = kh * 256 + q * 8;
    const int wrow  = (nn >> 2) * HD + j0 + (nn & 3);   // streamed W row

    const _Float16* wxp = wx16 + (size_t)wrow * HD + kbase;
    const _Float16* wlp = whl  + (size_t)wrow * HD + kbase;
    const _Float16* whp = (const _Float16*)&s_wh[nn * 1032 + kbase];

    for (int t = 0; t < T_STEPS; t++) {
        const int cur = t & 1;
        const _Float16* chp = chg + (size_t)cur * BH + (size_t)arow * HD + kbase;
        const _Float16* clp = clg + (size_t)cur * BH + (size_t)arow * HD + kbase;

        floatx4 acc = {0.f, 0.f, 0.f, 0.f};

        // ---- X part: pre += X[t] @ Wx^T ----
        if (XF16) {
            const _Float16* xp = xh + (size_t)t * BH + (size_t)arow * HD + kbase;
            #pragma unroll 4
            for (int k = 0; k < 256; k += 32) {
                half8 av = *(const half8*)(xp + k);
                half8 bv = *(const half8*)(wxp + k);
                acc = __builtin_amdgcn_mfma_f32_16x16x32_f16(av, bv, acc, 0, 0, 0);
            }
        } else {
            const float* xp = X + (size_t)t * BH + (size_t)arow * HD + kbase;
            #pragma unroll 4
            for (int k = 0; k < 256; k += 32) {
                float4v x0 = *(const float4v*)(xp + k);
                float4v x1 = *(const float4v*)(xp + k + 4);
                half8 av = cvt_h8(x0, x1);
                half8 bv = *(const half8*)(wxp + k);
                acc = __builtin_amdgcn_mfma_f32_16x16x32_f16(av, bv, acc, 0, 0, 0);
            }
        }

        // ---- c part: pre += c_prev @ Wh^T (3-product f16 split) ----
        #pragma unroll 4
        for (int k = 0; k < 256; k += 32) {
            half8 ah = *(const half8*)(chp + k);
            half8 al = *(const half8*)(clp + k);
            half8 bh = *(const half8*)(whp + k);
            half8 bl = *(const half8*)(wlp + k);
            acc = __builtin_amdgcn_mfma_f32_16x16x32_f16(ah, bh, acc, 0, 0, 0);
            acc = __builtin_amdgcn_mfma_f32_16x16x32_f16(al, bh, acc, 0, 0, 0);
            acc = __builtin_amdgcn_mfma_f32_16x16x32_f16(ah, bl, acc, 0, 0, 0);
        }

        // ---- partials to LDS ----
        s_pre[wave][q * 4 + 0][nn] = acc[0];
        s_pre[wave][q * 4 + 1][nn] = acc[1];
        s_pre[wave][q * 4 + 2][nn] = acc[2];
        s_pre[wave][q * 4 + 3][nn] = acc[3];
        __syncthreads();

        // ---- epilogue: 256 threads, one (b, jj) each ----
        if (tid < 256) {
            int b = tid >> 2, jj = tid & 3, j = j0 + jj;
            int m = b & 15, mtt = b >> 4;

            float pg[4];
            #pragma unroll
            for (int g = 0; g < 4; g++) {
                float s = 0.f;
                #pragma unroll
                for (int kk = 0; kk < 4; kk++)
                    s += s_pre[kk * 4 + mtt][m][g * 4 + jj];
                pg[g] = s + biasr[g];
            }

            float c_old = s_c[tid];
            float i_g = sigmoidf_(pg[0]);
            float f_g = sigmoidf_(pg[1]);
            float o_g = sigmoidf_(pg[2]);
            float g_g = tanhf(pg[3]);
            float c_new = f_g * c_old + i_g * g_g;
            float h_new = o_g * tanhf(c_new);

            int mv = mask[t * BATCH + b];
            float h_out = mv ? h_new : s_h[tid];
            float c_out = mv ? c_new : c_old;
            s_h[tid] = h_out;
            s_c[tid] = c_out;

            int nxt = cur ^ 1;
            _Float16 hi = (_Float16)c_out;
            chg[(size_t)nxt * BH + b * HD + j] = hi;
            clg[(size_t)nxt * BH + b * HD + j] = (_Float16)(c_out - (float)hi);
            out[(size_t)t * BH + b * HD + j] = h_out;

            if (t == T_STEPS - 1) {
                size_t tail = (size_t)T_STEPS * BH;
                out[tail + b * HD + j]      = h_out;   // h_last
                out[tail + BH + b * HD + j] = c_out;   // c_last
            }
        }
        grid_bar(barg, barr, t + 1);
    }
}

// ---------------- fallback (tiny ws): round-2 per-step kernel ----------------
__global__ void init_c_fb(const float* __restrict__ c0, float* __restrict__ cf,
                          _Float16* __restrict__ ch, _Float16* __restrict__ cl) {
    int i = blockIdx.x * 256 + threadIdx.x;
    if (i < BH) {
        float v = c0[i];
        cf[i] = v;
        _Float16 h = (_Float16)v;
        ch[i] = h;
        cl[i] = (_Float16)(v - (float)h);
    }
}

__global__ __launch_bounds__(1024) void lstm_step_fb(
    const float* __restrict__ X, const float* __restrict__ h0,
    const float* __restrict__ Wx, const float* __restrict__ Wh,
    const float* __restrict__ bias, const int* __restrict__ mask,
    float* __restrict__ cf, _Float16* __restrict__ chbuf, _Float16* __restrict__ clbuf,
    float* __restrict__ out, int t)
{
    __shared__ float lds_pre[4][64][16];
    const int tid = threadIdx.x, wave = tid >> 6, lane = tid & 63;
    const int g = wave & 3, mt = wave >> 2, j0 = blockIdx.x * 16;
    const int cur = t & 1;
    const float* cf_prev = cf + (size_t)cur * BH;
    const _Float16* ch_prev = chbuf + (size_t)cur * BH;
    const _Float16* cl_prev = clbuf + (size_t)cur * BH;
    float* cf_next = cf + (size_t)(cur ^ 1) * BH;
    _Float16* ch_next = chbuf + (size_t)(cur ^ 1) * BH;
    _Float16* cl_next = clbuf + (size_t)(cur ^ 1) * BH;
    const int arow = mt * 16 + (lane & 15);
    const int brow = g * HD + j0 + (lane & 15);
    const int koff = (lane >> 4) * 8;
    floatx4 acc = {0.f, 0.f, 0.f, 0.f};
    {
        const float* xp = X + (size_t)t * BH + (size_t)arow * HD + koff;
        const float* wp = Wx + (size_t)brow * HD + koff;
        #pragma unroll 4
        for (int k = 0; k < HD; k += 32) {
            float4v x0 = *(const float4v*)(xp + k);
            float4v x1 = *(const float4v*)(xp + k + 4);
            float4v w0 = *(const float4v*)(wp + k);
            float4v w1 = *(const float4v*)(wp + k + 4);
            acc = __builtin_amdgcn_mfma_f32_16x16x32_f16(cvt_h8(x0, x1), cvt_h8(w0, w1), acc, 0, 0, 0);
        }
    }
    {
        const _Float16* chp = ch_prev + (size_t)arow * HD + koff;
        const _Float16* clp = cl_prev + (size_t)arow * HD + koff;
        const float* whp = Wh + (size_t)brow * HD + koff;
        #pragma unroll 4
        for (int k = 0; k < HD; k += 32) {
            half8 ah = *(const half8*)(chp + k);
            half8 al = *(const half8*)(clp + k);
            float4v w0 = *(const float4v*)(whp + k);
            float4v w1 = *(const float4v*)(whp + k + 4);
            half8 bh = cvt_h8(w0, w1);
            float4v r0, r1;
            r0[0] = w0[0] - (float)bh[0]; r0[1] = w0[1] - (float)bh[1];
            r0[2] = w0[2] - (float)bh[2]; r0[3] = w0[3] - (float)bh[3];
            r1[0] = w1[0] - (float)bh[4]; r1[1] = w1[1] - (float)bh[5];
            r1[2] = w1[2] - (float)bh[6]; r1[3] = w1[3] - (float)bh[7];
            half8 bl = cvt_h8(r0, r1);
            acc = __builtin_amdgcn_mfma_f32_16x16x32_f16(ah, bh, acc, 0, 0, 0);
            acc = __builtin_amdgcn_mfma_f32_16x16x32_f16(al, bh, acc, 0, 0, 0);
            acc = __builtin_amdgcn_mfma_f32_16x16x32_f16(ah, bl, acc, 0, 0, 0);
        }
    }
    {
        const int qq = lane >> 4, col = lane & 15;
        lds_pre[g][mt * 16 + qq * 4 + 0][col] = acc[0];
        lds_pre[g][mt * 16 + qq * 4 + 1][col] = acc[1];
        lds_pre[g][mt * 16 + qq * 4 + 2][col] = acc[2];
        lds_pre[g][mt * 16 + qq * 4 + 3][col] = acc[3];
    }
    __syncthreads();
    {
        const int bl2 = tid >> 4, n = tid & 15, j = j0 + n;
        float pg[4];
        #pragma unroll
        for (int gg = 0; gg < 4; gg++) pg[gg] = lds_pre[gg][bl2][n] + bias[gg * HD + j];
        float c_old = cf_prev[bl2 * HD + j];
        float i_g = sigmoidf_(pg[0]), f_g = sigmoidf_(pg[1]);
        float o_g = sigmoidf_(pg[2]), g_g = tanhf(pg[3]);
        float c_new = f_g * c_old + i_g * g_g;
        float h_new = o_g * tanhf(c_new);
        int mv = mask[t * BATCH + bl2];
        float h_prev = (t == 0) ? h0[bl2 * HD + j] : out[(size_t)(t - 1) * BH + bl2 * HD + j];
        float h_out = mv ? h_new : h_prev;
        float c_out = mv ? c_new : c_old;
        cf_next[bl2 * HD + j] = c_out;
        _Float16 hh = (_Float16)c_out;
        ch_next[bl2 * HD + j] = hh;
        cl_next[bl2 * HD + j] = (_Float16)(c_out - (float)hh);
        out[(size_t)t * BH + bl2 * HD + j] = h_out;
        if (t == T_STEPS - 1) {
            size_t tail = (size_t)T_STEPS * BH;
            out[tail + bl2 * HD + j] = h_out;
            out[tail + BH + bl2 * HD + j] = c_out;
        }
    }
}

// ---------------- launch ----------------
extern "C" void kernel_launch(void* const* d_in, const int* in_sizes, int n_in,
                              void* d_out, int out_size, void* d_ws, size_t ws_size,
                              hipStream_t stream) {
    const float* X    = (const float*)d_in[0];
    const float* h0   = (const float*)d_in[1];
    const float* c0   = (const float*)d_in[2];
    const int*   mask = (const int*)  d_in[3];
    const float* Wx   = (const float*)d_in[4];
    const float* Wh   = (const float*)d_in[5];
    const float* bias = (const float*)d_in[6];
    float* out = (float*)d_out;
    char* ws = (char*)d_ws;

    if (ws_size >= TIER_B_WS) {
        int*      barg = (int*)(ws + BAR_GRP_OFF);
        int*      barr = (int*)(ws + BAR_ROOT_OFF);
        _Float16* chg  = (_Float16*)(ws + CH_OFF);
        _Float16* clg  = (_Float16*)(ws + CL_OFF);
        _Float16* wx16 = (_Float16*)(ws + WX_OFF);
        _Float16* whh  = (_Float16*)(ws + WHH_OFF);
        _Float16* whl  = (_Float16*)(ws + WHL_OFF);
        _Float16* xh   = (_Float16*)(ws + XH_OFF);

        prep_zero<<<dim3(24), dim3(256), 0, stream>>>(barg);
        prep_w<<<dim3(16384), dim3(256), 0, stream>>>(Wx, Wh, wx16, whh, whl);

        const bool tierA = ws_size >= TIER_A_WS;
        if (tierA)
            prep_x<<<dim3(131072), dim3(256), 0, stream>>>(X, xh);

        void* args[] = {
            (void*)&X, (void*)&xh, (void*)&h0, (void*)&c0, (void*)&bias,
            (void*)&mask, (void*)&wx16, (void*)&whh, (void*)&whl,
            (void*)&chg, (void*)&clg, (void*)&barg, (void*)&barr, (void*)&out
        };
        if (tierA)
            hipLaunchCooperativeKernel((const void*)&lstm_persist<true>,
                                       dim3(NBLK), dim3(1024), args, 0, stream);
        else
            hipLaunchCooperativeKernel((const void*)&lstm_persist<false>,
                                       dim3(NBLK), dim3(1024), args, 0, stream);
    } else {
        // fallback: per-step kernels, in-register weight conversion (ws >= 1MB)
        float*    cf = (float*)ws;
        _Float16* ch = (_Float16*)(ws + 524288);
        _Float16* cl = (_Float16*)(ws + 786432);
        init_c_fb<<<dim3((BH + 255) / 256), dim3(256), 0, stream>>>(c0, cf, ch, cl);
        for (int t = 0; t < T_STEPS; t++)
            lstm_step_fb<<<dim3(64), dim3(1024), 0, stream>>>(
                X, h0, Wx, Wh, bias, mask, cf, ch, cl, out, t);
    }
}

// Round 4
// 11842.613 us; speedup vs baseline: 4.3433x; 1.3636x over previous
//
#include <hip/hip_runtime.h>
#include <cstdint>
#include <cstddef>

#define T_STEPS 512
#define BATCH   64
#define HD      1024
#define BH      (BATCH * HD)   // 65536
#define NBLK    256

using half8   = __attribute__((ext_vector_type(8))) _Float16;
using half4   = __attribute__((ext_vector_type(4))) _Float16;
using floatx4 = __attribute__((ext_vector_type(4))) float;
using float4v = __attribute__((ext_vector_type(4))) float;

__device__ __forceinline__ float sigmoidf_(float x) { return 1.0f / (1.0f + __expf(-x)); }

__device__ __forceinline__ half8 cvt_h8(float4v a, float4v b) {
    half8 r;
    r[0] = (_Float16)a[0]; r[1] = (_Float16)a[1];
    r[2] = (_Float16)a[2]; r[3] = (_Float16)a[3];
    r[4] = (_Float16)b[0]; r[5] = (_Float16)b[1];
    r[6] = (_Float16)b[2]; r[7] = (_Float16)b[3];
    return r;
}

// ---------------- workspace layout ----------------
static const size_t BAR_GRP_OFF  = 0;        // 513 slots * 8 ints
static const size_t BAR_ROOT_OFF = 20480;    // 513 ints
static const size_t CH_OFF  = 24576;                               // 256 KB
static const size_t CL_OFF  = CH_OFF + (size_t)2 * BH * 2;         // 256 KB
static const size_t WX_OFF  = 1u << 20;                            // 8 MB
static const size_t WHH_OFF = WX_OFF  + (size_t)8 * 1024 * 1024;   // 8 MB
static const size_t WHL_OFF = WHH_OFF + (size_t)8 * 1024 * 1024;   // 8 MB
static const size_t XH_OFF  = WHL_OFF + (size_t)8 * 1024 * 1024;   // @25MB
static const size_t X4_OFF  = XH_OFF;                              // tier A2: X4 f16 [32768][4096]
static const size_t TIER_A2_WS = X4_OFF + (size_t)32768 * 4096 * 2;  // ~281 MB
static const size_t TIER_A_WS  = XH_OFF + (size_t)T_STEPS * BH * 2;  // 89 MB
static const size_t TIER_B_WS  = XH_OFF;                             // 25 MB

// ---------------- prep kernels ----------------
__global__ void prep_zero(int* bar) {
    int i = blockIdx.x * 256 + threadIdx.x;
    if (i < 6144) bar[i] = 0;
}

__global__ void prep_w(const float* __restrict__ Wx, const float* __restrict__ Wh,
                       _Float16* __restrict__ wx16,
                       _Float16* __restrict__ whh, _Float16* __restrict__ whl) {
    int i = blockIdx.x * 256 + threadIdx.x;
    if (i < 4 * HD * HD) {
        wx16[i] = (_Float16)Wx[i];
        float w = Wh[i];
        _Float16 h = (_Float16)w;
        whh[i] = h;
        whl[i] = (_Float16)(w - (float)h);
    }
}

__global__ void prep_x(const float* __restrict__ X, _Float16* __restrict__ xh) {
    size_t i = (size_t)blockIdx.x * 256 + threadIdx.x;
    if (i < (size_t)T_STEPS * BH) xh[i] = (_Float16)X[i];
}

// ---------------- X4 GEMM: x4[32768][4096] = X[32768][1024] @ wx16^T ----------------
// 128x128 tile, K-chunk 32, 256 threads = 4 waves (2x2 of 64x64).
__global__ __launch_bounds__(256) void x4_gemm(
    const float* __restrict__ X,
    const _Float16* __restrict__ wx16,
    _Float16* __restrict__ x4)
{
    __shared__ _Float16 sA[128][40];
    __shared__ _Float16 sB[128][40];

    const int tid  = threadIdx.x;
    const int wave = tid >> 6;
    const int lane = tid & 63;
    const int m0 = blockIdx.x * 128, n0 = blockIdx.y * 128;
    const int wm = (wave & 1) * 64,  wn = (wave >> 1) * 64;
    const int fm = lane & 15, q = lane >> 4;

    floatx4 acc[4][4];
    #pragma unroll
    for (int i = 0; i < 4; i++)
        #pragma unroll
        for (int j = 0; j < 4; j++)
            acc[i][j] = (floatx4){0.f, 0.f, 0.f, 0.f};

    for (int k0 = 0; k0 < 1024; k0 += 32) {
        // stage A (f32 -> f16): 8 lanes cover one row's 32 floats (128B contiguous)
        {
            const int kq = (tid & 7) * 4;
            const int rb = tid >> 3;   // 0..31
            #pragma unroll
            for (int it = 0; it < 4; it++) {
                int row = rb + it * 32;
                float4v v = *(const float4v*)(X + (size_t)(m0 + row) * 1024 + k0 + kq);
                half4 h; h[0] = (_Float16)v[0]; h[1] = (_Float16)v[1];
                h[2] = (_Float16)v[2]; h[3] = (_Float16)v[3];
                *(half4*)&sA[row][kq] = h;
            }
        }
        // stage B (f16 copy)
        {
            const int half = tid & 1;
            const int row  = tid >> 1;  // 0..127
            const _Float16* src = wx16 + (size_t)(n0 + row) * 1024 + k0 + half * 16;
            *(half8*)&sB[row][half * 16]     = *(const half8*)(src);
            *(half8*)&sB[row][half * 16 + 8] = *(const half8*)(src + 8);
        }
        __syncthreads();

        half8 af[4], bf[4];
        #pragma unroll
        for (int i = 0; i < 4; i++) af[i] = *(const half8*)&sA[wm + 16 * i + fm][q * 8];
        #pragma unroll
        for (int j = 0; j < 4; j++) bf[j] = *(const half8*)&sB[wn + 16 * j + fm][q * 8];
        #pragma unroll
        for (int i = 0; i < 4; i++)
            #pragma unroll
            for (int j = 0; j < 4; j++)
                acc[i][j] = __builtin_amdgcn_mfma_f32_16x16x32_f16(af[i], bf[j], acc[i][j], 0, 0, 0);
        __syncthreads();
    }

    #pragma unroll
    for (int i = 0; i < 4; i++)
        #pragma unroll
        for (int j = 0; j < 4; j++)
            #pragma unroll
            for (int r = 0; r < 4; r++) {
                int row = m0 + wm + 16 * i + q * 4 + r;
                int col = n0 + wn + 16 * j + fm;
                x4[(size_t)row * 4096 + col] = (_Float16)acc[i][j][r];
            }
}

// ---------------- grid barrier (tree: 8 groups of 32 -> root) ----------------
__device__ __forceinline__ void grid_bar(int* grp, int* root, int slot) {
    __syncthreads();
    if (threadIdx.x == 0) {
        int g = blockIdx.x >> 5;
        int v = __hip_atomic_fetch_add(&grp[slot * 8 + g], 1,
                                       __ATOMIC_ACQ_REL, __HIP_MEMORY_SCOPE_AGENT);
        if (v == 31)
            __hip_atomic_fetch_add(&root[slot], 1,
                                   __ATOMIC_ACQ_REL, __HIP_MEMORY_SCOPE_AGENT);
        while (__hip_atomic_load(&root[slot], __ATOMIC_RELAXED,
                                 __HIP_MEMORY_SCOPE_AGENT) < 8)
            __builtin_amdgcn_s_sleep(2);
        (void)__hip_atomic_load(&root[slot], __ATOMIC_ACQUIRE,
                                __HIP_MEMORY_SCOPE_AGENT);
    }
    __syncthreads();
}

// ---------------- persistent recurrence (tier A2): X4 precomputed ----------------
// 256 blocks x 1024 threads. Block owns 4 cols x 4 gates. Wave: mt=w&3 (batch
// tile), kh=w>>2 (K chunk of 256). whh in LDS, whl in registers, c hi/lo global.
__global__ __launch_bounds__(1024, 4) void lstm_persist2(
    const _Float16* __restrict__ x4,   // [T*B][4096]
    const float* __restrict__ h0, const float* __restrict__ c0,
    const float* __restrict__ bias, const int* __restrict__ mask,
    const _Float16* __restrict__ whh, const _Float16* __restrict__ whl,
    _Float16* __restrict__ chg, _Float16* __restrict__ clg,
    int* __restrict__ barg, int* __restrict__ barr,
    float* __restrict__ out)
{
    __shared__ _Float16 s_wh[16 * 1032];    // 33 KB
    __shared__ float    s_pre[16][16][17];  // 17.4 KB
    __shared__ float    s_h[256], s_c[256];

    const int tid  = threadIdx.x;
    const int wave = tid >> 6;
    const int lane = tid & 63;
    const int j0   = blockIdx.x * 4;

    for (int idx = tid; idx < 2048; idx += 1024) {
        int n  = idx >> 7;
        int kk = (idx & 127) << 3;
        int r  = (n >> 2) * HD + j0 + (n & 3);
        *(half8*)&s_wh[n * 1032 + kk] = *(const half8*)(whh + (size_t)r * HD + kk);
    }

    float biasr[4] = {0.f, 0.f, 0.f, 0.f};
    if (tid < 256) {
        int b = tid >> 2, jj = tid & 3, j = j0 + jj;
        float cv = c0[b * HD + j];
        s_c[tid] = cv;
        s_h[tid] = h0[b * HD + j];
        _Float16 hi = (_Float16)cv;
        chg[b * HD + j] = hi;
        clg[b * HD + j] = (_Float16)(cv - (float)hi);
        #pragma unroll
        for (int g = 0; g < 4; g++) biasr[g] = bias[g * HD + j];
    }

    const int mt    = wave & 3;
    const int kh    = wave >> 2;
    const int arow  = mt * 16 + (lane & 15);
    const int nn    = lane & 15;
    const int q     = lane >> 4;
    const int kbase = kh * 256 + q * 8;
    const int wrow  = (nn >> 2) * HD + j0 + (nn & 3);

    // whl fragments -> registers (t-invariant, immune to barrier L2 invalidates)
    half8 wl[8];
    #pragma unroll
    for (int k = 0; k < 8; k++)
        wl[k] = *(const half8*)(whl + (size_t)wrow * HD + kbase + k * 32);
    const _Float16* whp = &s_wh[nn * 1032 + kbase];

    grid_bar(barg, barr, 0);

    for (int t = 0; t < T_STEPS; t++) {
        const int cur = t & 1;
        const _Float16* chp = chg + (size_t)cur * BH + (size_t)arow * HD + kbase;
        const _Float16* clp = clg + (size_t)cur * BH + (size_t)arow * HD + kbase;

        floatx4 acc = {0.f, 0.f, 0.f, 0.f};
        #pragma unroll
        for (int k = 0; k < 8; k++) {
            half8 ah = *(const half8*)(chp + k * 32);
            half8 al = *(const half8*)(clp + k * 32);
            half8 bh = *(const half8*)(whp + k * 32);
            acc = __builtin_amdgcn_mfma_f32_16x16x32_f16(ah, bh, acc, 0, 0, 0);
            acc = __builtin_amdgcn_mfma_f32_16x16x32_f16(al, bh, acc, 0, 0, 0);
            acc = __builtin_amdgcn_mfma_f32_16x16x32_f16(ah, wl[k], acc, 0, 0, 0);
        }

        s_pre[wave][q * 4 + 0][nn] = acc[0];
        s_pre[wave][q * 4 + 1][nn] = acc[1];
        s_pre[wave][q * 4 + 2][nn] = acc[2];
        s_pre[wave][q * 4 + 3][nn] = acc[3];
        __syncthreads();

        if (tid < 256) {
            int b = tid >> 2, jj = tid & 3, j = j0 + jj;
            int m = b & 15, mtt = b >> 4;

            float pg[4];
            #pragma unroll
            for (int g = 0; g < 4; g++) {
                float s = 0.f;
                #pragma unroll
                for (int kk = 0; kk < 4; kk++)
                    s += s_pre[kk * 4 + mtt][m][g * 4 + jj];
                pg[g] = s + biasr[g]
                      + (float)x4[((size_t)t * BATCH + b) * 4096 + g * HD + j];
            }

            float c_old = s_c[tid];
            float i_g = sigmoidf_(pg[0]);
            float f_g = sigmoidf_(pg[1]);
            float o_g = sigmoidf_(pg[2]);
            float g_g = tanhf(pg[3]);
            float c_new = f_g * c_old + i_g * g_g;
            float h_new = o_g * tanhf(c_new);

            int mv = mask[t * BATCH + b];
            float h_out = mv ? h_new : s_h[tid];
            float c_out = mv ? c_new : c_old;
            s_h[tid] = h_out;
            s_c[tid] = c_out;

            int nxt = cur ^ 1;
            _Float16 hi = (_Float16)c_out;
            chg[(size_t)nxt * BH + b * HD + j] = hi;
            clg[(size_t)nxt * BH + b * HD + j] = (_Float16)(c_out - (float)hi);
            out[(size_t)t * BH + b * HD + j] = h_out;

            if (t == T_STEPS - 1) {
                size_t tail = (size_t)T_STEPS * BH;
                out[tail + b * HD + j]      = h_out;
                out[tail + BH + b * HD + j] = c_out;
            }
        }
        grid_bar(barg, barr, t + 1);
    }
}

// ---------------- tier A/B persistent kernel (round-3, proven) ----------------
template<bool XF16>
__global__ __launch_bounds__(1024, 4) void lstm_persist(
    const float* __restrict__ X, const _Float16* __restrict__ xh,
    const float* __restrict__ h0, const float* __restrict__ c0,
    const float* __restrict__ bias, const int* __restrict__ mask,
    const _Float16* __restrict__ wx16, const _Float16* __restrict__ whh,
    const _Float16* __restrict__ whl,
    _Float16* __restrict__ chg, _Float16* __restrict__ clg,
    int* __restrict__ barg, int* __restrict__ barr,
    float* __restrict__ out)
{
    __shared__ _Float16 s_wh[16 * 1032];
    __shared__ float    s_pre[16][16][17];
    __shared__ float    s_h[256], s_c[256];

    const int tid  = threadIdx.x;
    const int wave = tid >> 6;
    const int lane = tid & 63;
    const int j0   = blockIdx.x * 4;

    for (int idx = tid; idx < 2048; idx += 1024) {
        int n  = idx >> 7;
        int kk = (idx & 127) << 3;
        int r  = (n >> 2) * HD + j0 + (n & 3);
        *(half8*)&s_wh[n * 1032 + kk] = *(const half8*)(whh + (size_t)r * HD + kk);
    }

    float biasr[4] = {0.f, 0.f, 0.f, 0.f};
    if (tid < 256) {
        int b = tid >> 2, jj = tid & 3, j = j0 + jj;
        float cv = c0[b * HD + j];
        s_c[tid] = cv;
        s_h[tid] = h0[b * HD + j];
        _Float16 hi = (_Float16)cv;
        chg[b * HD + j] = hi;
        clg[b * HD + j] = (_Float16)(cv - (float)hi);
        #pragma unroll
        for (int g = 0; g < 4; g++) biasr[g] = bias[g * HD + j];
    }
    grid_bar(barg, barr, 0);

    const int mt    = wave & 3;
    const int kh    = wave >> 2;
    const int arow  = mt * 16 + (lane & 15);
    const int nn    = lane & 15;
    const int q     = lane >> 4;
    const int kbase = kh * 256 + q * 8;
    const int wrow  = (nn >> 2) * HD + j0 + (nn & 3);

    const _Float16* wxp = wx16 + (size_t)wrow * HD + kbase;
    const _Float16* wlp = whl  + (size_t)wrow * HD + kbase;
    const _Float16* whp = (const _Float16*)&s_wh[nn * 1032 + kbase];

    for (int t = 0; t < T_STEPS; t++) {
        const int cur = t & 1;
        const _Float16* chp = chg + (size_t)cur * BH + (size_t)arow * HD + kbase;
        const _Float16* clp = clg + (size_t)cur * BH + (size_t)arow * HD + kbase;

        floatx4 acc = {0.f, 0.f, 0.f, 0.f};

        if (XF16) {
            const _Float16* xp = xh + (size_t)t * BH + (size_t)arow * HD + kbase;
            #pragma unroll 4
            for (int k = 0; k < 256; k += 32) {
                half8 av = *(const half8*)(xp + k);
                half8 bv = *(const half8*)(wxp + k);
                acc = __builtin_amdgcn_mfma_f32_16x16x32_f16(av, bv, acc, 0, 0, 0);
            }
        } else {
            const float* xp = X + (size_t)t * BH + (size_t)arow * HD + kbase;
            #pragma unroll 4
            for (int k = 0; k < 256; k += 32) {
                float4v x0 = *(const float4v*)(xp + k);
                float4v x1 = *(const float4v*)(xp + k + 4);
                half8 av = cvt_h8(x0, x1);
                half8 bv = *(const half8*)(wxp + k);
                acc = __builtin_amdgcn_mfma_f32_16x16x32_f16(av, bv, acc, 0, 0, 0);
            }
        }

        #pragma unroll 4
        for (int k = 0; k < 256; k += 32) {
            half8 ah = *(const half8*)(chp + k);
            half8 al = *(const half8*)(clp + k);
            half8 bh = *(const half8*)(whp + k);
            half8 bl = *(const half8*)(wlp + k);
            acc = __builtin_amdgcn_mfma_f32_16x16x32_f16(ah, bh, acc, 0, 0, 0);
            acc = __builtin_amdgcn_mfma_f32_16x16x32_f16(al, bh, acc, 0, 0, 0);
            acc = __builtin_amdgcn_mfma_f32_16x16x32_f16(ah, bl, acc, 0, 0, 0);
        }

        s_pre[wave][q * 4 + 0][nn] = acc[0];
        s_pre[wave][q * 4 + 1][nn] = acc[1];
        s_pre[wave][q * 4 + 2][nn] = acc[2];
        s_pre[wave][q * 4 + 3][nn] = acc[3];
        __syncthreads();

        if (tid < 256) {
            int b = tid >> 2, jj = tid & 3, j = j0 + jj;
            int m = b & 15, mtt = b >> 4;

            float pg[4];
            #pragma unroll
            for (int g = 0; g < 4; g++) {
                float s = 0.f;
                #pragma unroll
                for (int kk = 0; kk < 4; kk++)
                    s += s_pre[kk * 4 + mtt][m][g * 4 + jj];
                pg[g] = s + biasr[g];
            }

            float c_old = s_c[tid];
            float i_g = sigmoidf_(pg[0]);
            float f_g = sigmoidf_(pg[1]);
            float o_g = sigmoidf_(pg[2]);
            float g_g = tanhf(pg[3]);
            float c_new = f_g * c_old + i_g * g_g;
            float h_new = o_g * tanhf(c_new);

            int mv = mask[t * BATCH + b];
            float h_out = mv ? h_new : s_h[tid];
            float c_out = mv ? c_new : c_old;
            s_h[tid] = h_out;
            s_c[tid] = c_out;

            int nxt = cur ^ 1;
            _Float16 hi = (_Float16)c_out;
            chg[(size_t)nxt * BH + b * HD + j] = hi;
            clg[(size_t)nxt * BH + b * HD + j] = (_Float16)(c_out - (float)hi);
            out[(size_t)t * BH + b * HD + j] = h_out;

            if (t == T_STEPS - 1) {
                size_t tail = (size_t)T_STEPS * BH;
                out[tail + b * HD + j]      = h_out;
                out[tail + BH + b * HD + j] = c_out;
            }
        }
        grid_bar(barg, barr, t + 1);
    }
}

// ---------------- tiny-ws fallback: per-step kernel ----------------
__global__ void init_c_fb(const float* __restrict__ c0, float* __restrict__ cf,
                          _Float16* __restrict__ ch, _Float16* __restrict__ cl) {
    int i = blockIdx.x * 256 + threadIdx.x;
    if (i < BH) {
        float v = c0[i];
        cf[i] = v;
        _Float16 h = (_Float16)v;
        ch[i] = h;
        cl[i] = (_Float16)(v - (float)h);
    }
}

__global__ __launch_bounds__(1024) void lstm_step_fb(
    const float* __restrict__ X, const float* __restrict__ h0,
    const float* __restrict__ Wx, const float* __restrict__ Wh,
    const float* __restrict__ bias, const int* __restrict__ mask,
    float* __restrict__ cf, _Float16* __restrict__ chbuf, _Float16* __restrict__ clbuf,
    float* __restrict__ out, int t)
{
    __shared__ float lds_pre[4][64][16];
    const int tid = threadIdx.x, wave = tid >> 6, lane = tid & 63;
    const int g = wave & 3, mt = wave >> 2, j0 = blockIdx.x * 16;
    const int cur = t & 1;
    const float* cf_prev = cf + (size_t)cur * BH;
    const _Float16* ch_prev = chbuf + (size_t)cur * BH;
    const _Float16* cl_prev = clbuf + (size_t)cur * BH;
    float* cf_next = cf + (size_t)(cur ^ 1) * BH;
    _Float16* ch_next = chbuf + (size_t)(cur ^ 1) * BH;
    _Float16* cl_next = clbuf + (size_t)(cur ^ 1) * BH;
    const int arow = mt * 16 + (lane & 15);
    const int brow = g * HD + j0 + (lane & 15);
    const int koff = (lane >> 4) * 8;
    floatx4 acc = {0.f, 0.f, 0.f, 0.f};
    {
        const float* xp = X + (size_t)t * BH + (size_t)arow * HD + koff;
        const float* wp = Wx + (size_t)brow * HD + koff;
        #pragma unroll 4
        for (int k = 0; k < HD; k += 32) {
            float4v x0 = *(const float4v*)(xp + k);
            float4v x1 = *(const float4v*)(xp + k + 4);
            float4v w0 = *(const float4v*)(wp + k);
            float4v w1 = *(const float4v*)(wp + k + 4);
            acc = __builtin_amdgcn_mfma_f32_16x16x32_f16(cvt_h8(x0, x1), cvt_h8(w0, w1), acc, 0, 0, 0);
        }
    }
    {
        const _Float16* chp = ch_prev + (size_t)arow * HD + koff;
        const _Float16* clp = cl_prev + (size_t)arow * HD + koff;
        const float* whp = Wh + (size_t)brow * HD + koff;
        #pragma unroll 4
        for (int k = 0; k < HD; k += 32) {
            half8 ah = *(const half8*)(chp + k);
            half8 al = *(const half8*)(clp + k);
            float4v w0 = *(const float4v*)(whp + k);
            float4v w1 = *(const float4v*)(whp + k + 4);
            half8 bh = cvt_h8(w0, w1);
            float4v r0, r1;
            r0[0] = w0[0] - (float)bh[0]; r0[1] = w0[1] - (float)bh[1];
            r0[2] = w0[2] - (float)bh[2]; r0[3] = w0[3] - (float)bh[3];
            r1[0] = w1[0] - (float)bh[4]; r1[1] = w1[1] - (float)bh[5];
            r1[2] = w1[2] - (float)bh[6]; r1[3] = w1[3] - (float)bh[7];
            half8 bl = cvt_h8(r0, r1);
            acc = __builtin_amdgcn_mfma_f32_16x16x32_f16(ah, bh, acc, 0, 0, 0);
            acc = __builtin_amdgcn_mfma_f32_16x16x32_f16(al, bh, acc, 0, 0, 0);
            acc = __builtin_amdgcn_mfma_f32_16x16x32_f16(ah, bl, acc, 0, 0, 0);
        }
    }
    {
        const int qq = lane >> 4, col = lane & 15;
        lds_pre[g][mt * 16 + qq * 4 + 0][col] = acc[0];
        lds_pre[g][mt * 16 + qq * 4 + 1][col] = acc[1];
        lds_pre[g][mt * 16 + qq * 4 + 2][col] = acc[2];
        lds_pre[g][mt * 16 + qq * 4 + 3][col] = acc[3];
    }
    __syncthreads();
    {
        const int bl2 = tid >> 4, n = tid & 15, j = j0 + n;
        float pg[4];
        #pragma unroll
        for (int gg = 0; gg < 4; gg++) pg[gg] = lds_pre[gg][bl2][n] + bias[gg * HD + j];
        float c_old = cf_prev[bl2 * HD + j];
        float i_g = sigmoidf_(pg[0]), f_g = sigmoidf_(pg[1]);
        float o_g = sigmoidf_(pg[2]), g_g = tanhf(pg[3]);
        float c_new = f_g * c_old + i_g * g_g;
        float h_new = o_g * tanhf(c_new);
        int mv = mask[t * BATCH + bl2];
        float h_prev = (t == 0) ? h0[bl2 * HD + j] : out[(size_t)(t - 1) * BH + bl2 * HD + j];
        float h_out = mv ? h_new : h_prev;
        float c_out = mv ? c_new : c_old;
        cf_next[bl2 * HD + j] = c_out;
        _Float16 hh = (_Float16)c_out;
        ch_next[bl2 * HD + j] = hh;
        cl_next[bl2 * HD + j] = (_Float16)(c_out - (float)hh);
        out[(size_t)t * BH + bl2 * HD + j] = h_out;
        if (t == T_STEPS - 1) {
            size_t tail = (size_t)T_STEPS * BH;
            out[tail + bl2 * HD + j] = h_out;
            out[tail + BH + bl2 * HD + j] = c_out;
        }
    }
}

// ---------------- launch ----------------
extern "C" void kernel_launch(void* const* d_in, const int* in_sizes, int n_in,
                              void* d_out, int out_size, void* d_ws, size_t ws_size,
                              hipStream_t stream) {
    const float* X    = (const float*)d_in[0];
    const float* h0   = (const float*)d_in[1];
    const float* c0   = (const float*)d_in[2];
    const int*   mask = (const int*)  d_in[3];
    const float* Wx   = (const float*)d_in[4];
    const float* Wh   = (const float*)d_in[5];
    const float* bias = (const float*)d_in[6];
    float* out = (float*)d_out;
    char* ws = (char*)d_ws;

    if (ws_size >= TIER_B_WS) {
        int*      barg = (int*)(ws + BAR_GRP_OFF);
        int*      barr = (int*)(ws + BAR_ROOT_OFF);
        _Float16* chg  = (_Float16*)(ws + CH_OFF);
        _Float16* clg  = (_Float16*)(ws + CL_OFF);
        _Float16* wx16 = (_Float16*)(ws + WX_OFF);
        _Float16* whh  = (_Float16*)(ws + WHH_OFF);
        _Float16* whl  = (_Float16*)(ws + WHL_OFF);

        prep_zero<<<dim3(24), dim3(256), 0, stream>>>(barg);
        prep_w<<<dim3(16384), dim3(256), 0, stream>>>(Wx, Wh, wx16, whh, whl);

        if (ws_size >= TIER_A2_WS) {
            _Float16* x4 = (_Float16*)(ws + X4_OFF);
            x4_gemm<<<dim3(256, 32), dim3(256), 0, stream>>>(X, wx16, x4);
            void* args[] = {
                (void*)&x4, (void*)&h0, (void*)&c0, (void*)&bias, (void*)&mask,
                (void*)&whh, (void*)&whl, (void*)&chg, (void*)&clg,
                (void*)&barg, (void*)&barr, (void*)&out
            };
            hipLaunchCooperativeKernel((const void*)&lstm_persist2,
                                       dim3(NBLK), dim3(1024), args, 0, stream);
        } else {
            _Float16* xh = (_Float16*)(ws + XH_OFF);
            const bool tierA = ws_size >= TIER_A_WS;
            if (tierA)
                prep_x<<<dim3(131072), dim3(256), 0, stream>>>(X, xh);
            void* args[] = {
                (void*)&X, (void*)&xh, (void*)&h0, (void*)&c0, (void*)&bias,
                (void*)&mask, (void*)&wx16, (void*)&whh, (void*)&whl,
                (void*)&chg, (void*)&clg, (void*)&barg, (void*)&barr, (void*)&out
            };
            if (tierA)
                hipLaunchCooperativeKernel((const void*)&lstm_persist<true>,
                                           dim3(NBLK), dim3(1024), args, 0, stream);
            else
                hipLaunchCooperativeKernel((const void*)&lstm_persist<false>,
                                           dim3(NBLK), dim3(1024), args, 0, stream);
        }
    } else {
        float*    cf = (float*)ws;
        _Float16* ch = (_Float16*)(ws + 524288);
        _Float16* cl = (_Float16*)(ws + 786432);
        init_c_fb<<<dim3((BH + 255) / 256), dim3(256), 0, stream>>>(c0, cf, ch, cl);
        for (int t = 0; t < T_STEPS; t++)
            lstm_step_fb<<<dim3(64), dim3(1024), 0, stream>>>(
                X, h0, Wx, Wh, bias, mask, cf, ch, cl, out, t);
    }
}